// Round 1
// 954.014 us; speedup vs baseline: 1.0479x; 1.0479x over previous
//
#include <hip/hip_runtime.h>
#include <hip/hip_bf16.h>

#define N_NODES   50000
#define EDGES     1600000
#define D         128
#define K_INC     2000
#define K_TOT     2128   // 2000 (inc) + 128 (curr_h)
#define K_PAD     2176   // padded to multiple of 64 (34 * 64)
#define KTILES    34
#define LN_EPS    1e-5f

typedef float f32x4 __attribute__((ext_vector_type(4)));
typedef short short8 __attribute__((ext_vector_type(8)));   // 8 bf16 lanes (MFMA operand)
typedef ushort ushort8v __attribute__((ext_vector_type(8)));

__device__ __forceinline__ ushort f2bf(float x) {
    return __hip_bfloat16_raw(__float2bfloat16(x)).x;
}
__device__ __forceinline__ float bf_lo(uint v) { return __uint_as_float(v << 16); }
__device__ __forceinline__ float bf_hi(uint v) { return __uint_as_float(v & 0xffff0000u); }

// async global->LDS, 16B per lane, LDS dest = wave-uniform base + lane*16
#define GLOAD_LDS16(gp, lp) \
    __builtin_amdgcn_global_load_lds((const __attribute__((address_space(1))) void*)(gp), \
                                     (__attribute__((address_space(3))) void*)(lp), 16, 0, 0)

// ---------------- index-width probe: flag=1 if src looks like raw int64 ----------------
__global__ void probe_kernel(const int* __restrict__ src, int* __restrict__ flag) {
    __shared__ int any_nonzero;
    if (threadIdx.x == 0) any_nonzero = 0;
    __syncthreads();
    int v = src[threadIdx.x * 2 + 1];   // odd words all-zero iff little-endian int64, vals < 2^31
    if (v != 0) any_nonzero = 1;
    __syncthreads();
    if (threadIdx.x == 0) flag[0] = any_nonzero ? 0 : 1;
}

// ---------------- zero fill ----------------
__global__ void zero_kernel(int* __restrict__ p, int n) {
    int i = blockIdx.x * 256 + threadIdx.x;
    if (i < n) p[i] = 0;
}

// ---------------- degree histogram ----------------
__global__ void deg_kernel(const int* __restrict__ src, const int* __restrict__ dst,
                           const int* __restrict__ flag,
                           int* __restrict__ out_deg, int* __restrict__ in_cnt) {
    int e = blockIdx.x * 256 + threadIdx.x;
    int st = 1 + flag[0];
    if (e < EDGES) {
        atomicAdd(&out_deg[src[e * st]], 1);
        atomicAdd(&in_cnt[dst[e * st]], 1);
    }
}

// ---------------- one-block chunked exclusive scan over N ----------------
__global__ __launch_bounds__(1024) void scan_kernel(const int* __restrict__ cnt,
                                                    int* __restrict__ row_start) {
    __shared__ int buf[1024];
    int t = threadIdx.x;
    const int N = N_NODES;
    int chunk = (N + 1023) / 1024;
    int lo = t * chunk, hi = min(lo + chunk, N);
    int s = 0;
    for (int i = lo; i < hi; ++i) s += cnt[i];
    buf[t] = s;
    __syncthreads();
    for (int off = 1; off < 1024; off <<= 1) {
        int v = (t >= off) ? buf[t - off] : 0;
        __syncthreads();
        buf[t] += v;
        __syncthreads();
    }
    int run = (t > 0) ? buf[t - 1] : 0;
    for (int i = lo; i < hi; ++i) { row_start[i] = run; run += cnt[i]; }
    if (t == 1023) row_start[N] = buf[1023];
}

// ---------------- CSR scatter (dst-sorted src list) ----------------
__global__ void fill_kernel(const int* __restrict__ src, const int* __restrict__ dst,
                            const int* __restrict__ flag,
                            const int* __restrict__ row_start, int* __restrict__ cursor,
                            int* __restrict__ csr_src) {
    int e = blockIdx.x * 256 + threadIdx.x;
    int st = 1 + flag[0];
    if (e < EDGES) {
        int d = dst[e * st];
        int pos = atomicAdd(&cursor[d], 1);
        csr_src[row_start[d] + pos] = src[e * st];
    }
}

// ---------------- PbT[n][k] (bf16): k<K_INC -> (next_h @ (W_fus .* topDown_w))^T;
// ---------------- K_INC..K_TOT -> (W_conv .* conv_w)^T; rest zero ----------------
// 16 k-values per block: W_fus streamed once per 16 columns (8 MB total from L2),
// next_h reads are lane-uniform -> s_load. Boundaries 2000 and 2128 are multiples of 16.
#define PKB 16
__global__ __launch_bounds__(128) void p_kernel(
    const float* __restrict__ next_h, const float* __restrict__ W_fus,
    const float* __restrict__ topDown_w, const float* __restrict__ W_conv,
    const float* __restrict__ conv_w, ushort* __restrict__ PbT) {
    int n = threadIdx.x;
    int k0 = blockIdx.x * PKB;
    if (k0 < K_INC) {
        float acc[PKB];
#pragma unroll
        for (int t = 0; t < PKB; ++t) acc[t] = 0.f;
        for (int j = 0; j < D; ++j) {
            float w = W_fus[(size_t)j * D + n];
#pragma unroll
            for (int t = 0; t < PKB; ++t)
                acc[t] += next_h[(size_t)(k0 + t) * D + j] * w;   // uniform addr -> s_load
        }
        float tw = topDown_w[n];
#pragma unroll
        for (int t = 0; t < PKB; ++t)
            PbT[(size_t)n * K_PAD + k0 + t] = f2bf(acc[t] * tw);
    } else if (k0 < K_TOT) {
        float cw = conv_w[n];
#pragma unroll
        for (int t = 0; t < PKB; ++t)
            PbT[(size_t)n * K_PAD + k0 + t] = f2bf(W_conv[(size_t)(k0 + t - K_INC) * D + n] * cw);
    } else {
#pragma unroll
        for (int t = 0; t < PKB; ++t)
            PbT[(size_t)n * K_PAD + k0 + t] = 0;
    }
}

// ---------------- big GEMM: Zs(bf16) = ([inc | curr_h] @ PbT^T) * norm_out ----------------
// tile 64x128, BK=64, 256 threads (4 waves as 2x2 of 32x64 wave-tiles).
// Double-buffered, ONE barrier per K-tile: issue t+1 stage (A->regs, B->global_load_lds)
// before computing tile t. B LDS is linear (gload_lds requirement); bank conflicts fixed
// by both-sides XOR swizzle: pre-swizzled GLOBAL source + same XOR on ds_read address.
__global__ __launch_bounds__(256, 3) void gemm_kernel(
    const float* __restrict__ inc, const float* __restrict__ curr_h,
    const ushort* __restrict__ PbT, const int* __restrict__ out_deg,
    ushort* __restrict__ Zs) {
    __shared__ __align__(16) ushort As[2][64][72];      // padded [m][k] bf16 (reg-staged)
    __shared__ __align__(16) ushort Bs[2][128 * 64];    // linear [n][k] bf16 (gload_lds, swizzled)
    const int N = N_NODES;
    int tid = threadIdx.x;
    int wave = tid >> 6, lane = tid & 63;
    int wm = wave >> 1, wn = wave & 1;
    int r = lane & 15, q = lane >> 4;
    int rowBase = blockIdx.x * 64;

    f32x4 acc[2][4] = {};
    float4 aReg[2][2];

    auto stage_issue = [&](int kt, int nb) {
        int k0 = kt * 64;
        // A: 64 rows x 64 f32; each thread loads 8 consecutive f32 (2 x float4), 2 units
#pragma unroll
        for (int it = 0; it < 2; ++it) {
            int u = tid + it * 256;
            int arow = u >> 3, c8 = u & 7;
            int gk = k0 + c8 * 8;                       // K_INC, K_TOT are multiples of 8
            int grow = rowBase + arow; if (grow >= N) grow = N - 1;
            if (gk < K_INC) {
                const float4* p4 = (const float4*)(inc + (size_t)grow * K_INC + gk);
                aReg[it][0] = p4[0]; aReg[it][1] = p4[1];
            } else if (gk < K_TOT) {
                const float4* p4 = (const float4*)(curr_h + (size_t)grow * D + (gk - K_INC));
                aReg[it][0] = p4[0]; aReg[it][1] = p4[1];
            } else {
                aReg[it][0] = make_float4(0.f, 0.f, 0.f, 0.f);
                aReg[it][1] = make_float4(0.f, 0.f, 0.f, 0.f);
            }
        }
        // B: 128 rows x 64 bf16 = 16KB -> 16 wave-issues of 1KB. Linear LDS dest;
        // global source column pre-swizzled so swizzled ds_read reads it back straight.
#pragma unroll
        for (int it = 0; it < 4; ++it) {
            int chunk = tid + it * 256;                 // 0..1023, 16B each
            int n = chunk >> 3;                         // B row 0..127
            int c16 = (chunk & 7) << 4;                 // byte col within 128B row
            int gb = c16 ^ ((n & 7) << 4);              // inverse-swizzle the SOURCE
            const char* gp = (const char*)PbT + (size_t)n * (K_PAD * 2) + (size_t)(k0 * 2) + gb;
            char* lp = (char*)(&Bs[nb][0]) + it * 4096 + wave * 1024;  // wave-uniform base
            GLOAD_LDS16(gp, lp);
        }
    };
    auto stage_write = [&](int nb) {
#pragma unroll
        for (int it = 0; it < 2; ++it) {
            int u = tid + it * 256;
            int arow = u >> 3, c8 = u & 7;
            const float* f = (const float*)&aReg[it][0];
            ushort8v hv;
#pragma unroll
            for (int j = 0; j < 8; ++j) hv[j] = f2bf(f[j]);
            *(ushort8v*)&As[nb][arow][c8 * 8] = hv;     // b128, balanced banks (pad 72)
        }
    };

    // prologue: stage tile 0 into buf 0
    stage_issue(0, 0);
    stage_write(0);
    __syncthreads();

    int cur = 0;
    for (int kt = 0; kt < KTILES; ++kt) {
        int nb = cur ^ 1;
        if (kt + 1 < KTILES) stage_issue(kt + 1, nb);   // loads in flight under MFMA
#pragma unroll
        for (int kk = 0; kk < 2; ++kk) {
            short8 af[2], bfr[4];
#pragma unroll
            for (int mi = 0; mi < 2; ++mi)
                af[mi] = *(const short8*)&As[cur][wm * 32 + mi * 16 + r][kk * 32 + q * 8];
#pragma unroll
            for (int ni = 0; ni < 4; ++ni) {
                int brow = wn * 64 + ni * 16 + r;
                int bcol = (kk * 64 + q * 16) ^ ((r & 7) << 4);   // same XOR as source
                bfr[ni] = *(const short8*)((const char*)&Bs[cur][0] + brow * 128 + bcol);
            }
#pragma unroll
            for (int mi = 0; mi < 2; ++mi)
#pragma unroll
                for (int ni = 0; ni < 4; ++ni)
                    acc[mi][ni] = __builtin_amdgcn_mfma_f32_16x16x32_bf16(af[mi], bfr[ni], acc[mi][ni], 0, 0, 0);
        }
        if (kt + 1 < KTILES) stage_write(nb);           // vmcnt wait lands here, post-MFMA
        __syncthreads();                                // single barrier per K-tile
        cur = nb;
    }

#pragma unroll
    for (int mi = 0; mi < 2; ++mi) {
#pragma unroll
        for (int j = 0; j < 4; ++j) {
            int grow = rowBase + wm * 32 + mi * 16 + q * 4 + j;   // C/D: row = (lane>>4)*4 + reg [m89]
            if (grow < N) {
                float no = rsqrtf((float)(out_deg[grow] + 1));    // +1 self-loop
#pragma unroll
                for (int ni = 0; ni < 4; ++ni) {
                    int col = wn * 64 + ni * 16 + r;              // C/D: col = lane&15 [m89]
                    Zs[(size_t)grow * D + col] = f2bf(acc[mi][ni][j] * no);
                }
            }
        }
    }
}

// ---------------- fused aggregation + norm_in + bias + LayerNorm + ReLU ----------------
// 1 wave per node, 2 channels per lane (uint = bf16x2), 4 nodes per block.
// Edge indices loaded 64-at-a-time coalesced, broadcast via shfl; gathers unrolled x4.
__global__ __launch_bounds__(256) void agg_ln_kernel(
    const ushort* __restrict__ Zs, const int* __restrict__ row_start,
    const int* __restrict__ csr_src,
    const float* __restrict__ b_conv, const float* __restrict__ b_fus,
    const float* __restrict__ conv_w, const float* __restrict__ topDown_w,
    const float* __restrict__ gamma, const float* __restrict__ beta,
    float* __restrict__ out) {
    int wid = threadIdx.x >> 6, lane = threadIdx.x & 63;
    int node = blockIdx.x * 4 + wid;
    if (node >= N_NODES) return;
    int c0 = lane * 2;

    uint v = *(const uint*)(Zs + (size_t)node * D + c0);   // self-loop
    float a0 = bf_lo(v), a1 = bf_hi(v);
    int beg = row_start[node], end = row_start[node + 1];

    for (int base = beg; base < end; base += 64) {
        int rem = end - base;
        int cnt = rem < 64 ? rem : 64;
        int idx = 0;
        if (base + lane < end) idx = csr_src[base + lane];  // one coalesced load / 64 edges
        int i = 0;
        for (; i + 4 <= cnt; i += 4) {
            int s0 = __shfl(idx, i),     s1 = __shfl(idx, i + 1);
            int s2 = __shfl(idx, i + 2), s3 = __shfl(idx, i + 3);
            uint v0 = *(const uint*)(Zs + (size_t)s0 * D + c0);
            uint v1 = *(const uint*)(Zs + (size_t)s1 * D + c0);
            uint v2 = *(const uint*)(Zs + (size_t)s2 * D + c0);
            uint v3 = *(const uint*)(Zs + (size_t)s3 * D + c0);
            a0 += bf_lo(v0) + bf_lo(v1) + bf_lo(v2) + bf_lo(v3);
            a1 += bf_hi(v0) + bf_hi(v1) + bf_hi(v2) + bf_hi(v3);
        }
        for (; i < cnt; ++i) {
            int s0 = __shfl(idx, i);
            uint v0 = *(const uint*)(Zs + (size_t)s0 * D + c0);
            a0 += bf_lo(v0); a1 += bf_hi(v0);
        }
    }

    float nin = rsqrtf((float)(end - beg + 1));
    float y0 = a0 * nin + b_conv[c0] * conv_w[c0] + b_fus[c0] * topDown_w[c0];
    float y1 = a1 * nin + b_conv[c0 + 1] * conv_w[c0 + 1] + b_fus[c0 + 1] * topDown_w[c0 + 1];

    float s1v = y0 + y1, s2v = y0 * y0 + y1 * y1;
#pragma unroll
    for (int off = 1; off < 64; off <<= 1) {
        s1v += __shfl_xor(s1v, off);
        s2v += __shfl_xor(s2v, off);
    }
    float mu = s1v * (1.f / D);
    float var = s2v * (1.f / D) - mu * mu;
    float rstd = rsqrtf(var + LN_EPS);
    float r0 = (y0 - mu) * rstd * gamma[c0] + beta[c0];
    float r1 = (y1 - mu) * rstd * gamma[c0 + 1] + beta[c0 + 1];
    *(float2*)(out + (size_t)node * D + c0) = make_float2(fmaxf(r0, 0.f), fmaxf(r1, 0.f));
}

extern "C" void kernel_launch(void* const* d_in, const int* in_sizes, int n_in,
                              void* d_out, int out_size, void* d_ws, size_t ws_size,
                              hipStream_t stream) {
    const float* curr_h    = (const float*)d_in[0];
    const float* next_h    = (const float*)d_in[1];
    const float* inc       = (const float*)d_in[2];
    const int*   src       = (const int*)d_in[3];
    const int*   dst       = (const int*)d_in[4];
    const float* W_conv    = (const float*)d_in[5];
    const float* b_conv    = (const float*)d_in[6];
    const float* W_fus     = (const float*)d_in[7];
    const float* b_fus     = (const float*)d_in[8];
    const float* conv_w    = (const float*)d_in[9];
    const float* topDown_w = (const float*)d_in[10];
    const float* ln_gamma  = (const float*)d_in[11];
    const float* ln_beta   = (const float*)d_in[12];

    const int N = N_NODES;
    const int E = EDGES;

    // ---- workspace carve ----
    char* p = (char*)d_ws;
    ushort* Zs = (ushort*)p;     p += (size_t)N * D * sizeof(ushort);   // 12.8 MB (bf16)
    ushort* PbT = (ushort*)p;    p += (size_t)D * K_PAD * 2;            // 557 KB
    int* out_deg   = (int*)p;    p += (size_t)N * 4;                    // contiguous: out_deg,in_cnt,cursor
    int* in_cnt    = (int*)p;    p += (size_t)N * 4;
    int* cursor    = (int*)p;    p += (size_t)N * 4;
    int* row_start = (int*)p;    p += (size_t)(N + 1) * 4;
    int* idx_flag  = (int*)p;    p += 256;
    int* csr_src   = (int*)p;    p += (size_t)E * 4;

    probe_kernel<<<1, 1024, 0, stream>>>(src, idx_flag);
    zero_kernel<<<(3 * N + 255) / 256, 256, 0, stream>>>(out_deg, 3 * N);
    deg_kernel<<<(E + 255) / 256, 256, 0, stream>>>(src, dst, idx_flag, out_deg, in_cnt);
    scan_kernel<<<1, 1024, 0, stream>>>(in_cnt, row_start);
    fill_kernel<<<(E + 255) / 256, 256, 0, stream>>>(src, dst, idx_flag, row_start, cursor, csr_src);
    p_kernel<<<K_PAD / PKB, 128, 0, stream>>>(next_h, W_fus, topDown_w, W_conv, conv_w, PbT);
    gemm_kernel<<<(N + 63) / 64, 256, 0, stream>>>(inc, curr_h, PbT, out_deg, Zs);
    agg_ln_kernel<<<(N + 3) / 4, 256, 0, stream>>>(Zs, row_start, csr_src,
                                                   b_conv, b_fus, conv_w, topDown_w,
                                                   ln_gamma, ln_beta, (float*)d_out);
}